// Round 4
// baseline (533.223 us; speedup 1.0000x reference)
//
#include <hip/hip_runtime.h>
#include <hip/hip_bf16.h>

typedef __bf16 bf16;
typedef __bf16 bf16x8 __attribute__((ext_vector_type(8)));
typedef float  f32x4  __attribute__((ext_vector_type(4)));

static constexpr int NB  = 16;
static constexpr int NN  = 2048;
static constexpr int HID = 128;

// async 16B global -> LDS. LDS dest is wave-uniform base (+ lane*16 in HW);
// global src address IS per-lane (must carry the lane term!).
__device__ __forceinline__ void gload_lds16(const bf16* g, bf16* l) {
    __builtin_amdgcn_global_load_lds(
        (const __attribute__((address_space(1))) unsigned int*)g,
        (__attribute__((address_space(3))) unsigned int*)l, 16, 0, 0);
}

#define WAITV(n) asm volatile("s_waitcnt vmcnt(" #n ")" ::: "memory")

// ---------------------------------------------------------------------------
// Layouts:
//  B-tile (16 KB, 1024 chunks): chunk p = n*8 + (kc ^ (n&7)); content
//    h[node = kk*64 + kc*8 .. +8][n].  xTt/hT: [b][kk(32)][1024 ch].
//  A-tile (8 KB, 512 chunks) in MFMA-FRAGMENT order: chunk p = wr*128 +
//    ks*64 + q*16 + c0; content adj[rowbase + wr*16 + c0][kk*64 + ks*32 +
//    q*8 .. +8].  adjT: [b][mt(32)][kk(32)][512 ch].  A wave's per-K-step
//    fragment = 2 contiguous 1KB dwordx4 loads -> registers, no LDS.
//  WTg per layer (32 KB, 2048 chunks): chunk = n*16 + half*8 + (kc8^(n&7)),
//    half = k>>6, kc8 = (k&63)>>3  (k-contig bf16x8 frags of W^T[n][k])
// ---------------------------------------------------------------------------

// prep: W (128x128 fp32, [k][n]) -> swizzled WT tiles, for all 3 layers
__global__ __launch_bounds__(256) void prep_wt(const float* __restrict__ W0,
                                               const float* __restrict__ W1,
                                               const float* __restrict__ W2,
                                               bf16* __restrict__ WTg) {
    int l = blockIdx.x;
    const float* W = (l == 0) ? W0 : (l == 1) ? W1 : W2;
    bf16* out = WTg + l * 16384;
    int tid = threadIdx.x;
#pragma unroll
    for (int i = 0; i < 8; ++i) {
        int p = i * 256 + tid;                 // [0,2048)
        int n = p >> 4, half = (p >> 3) & 1, cs = p & 7;
        int kc = cs ^ (n & 7);
        int kbase = half * 64 + kc * 8;
        bf16x8 o;
#pragma unroll
        for (int r = 0; r < 8; ++r) o[r] = (bf16)W[(kbase + r) * 128 + n];
        *(bf16x8*)(out + p * 8) = o;
    }
}

// prep: x (16,2048,128) fp32 -> xTt tiled bf16 B-tiles
__global__ __launch_bounds__(256) void prep_xt(const float* __restrict__ x,
                                               bf16* __restrict__ xTt) {
    __shared__ bf16 T[128 * 136];
    const int blk = blockIdx.x;            // 256 blocks: 16 node-tiles x 16 b
    const int b = blk >> 4, node0 = (blk & 15) * 128;
    const int tid = threadIdx.x;
    const float* xb = x + ((size_t)b * NN + node0) * HID;
#pragma unroll
    for (int i = 0; i < 64; ++i) {
        int idx = i * 256 + tid;
        int node = idx >> 7, hid = idx & 127;
        T[hid * 136 + node] = (bf16)xb[(size_t)node * HID + hid];
    }
    __syncthreads();
#pragma unroll
    for (int i = 0; i < 8; ++i) {
        int p = i * 256 + tid;                 // [0,2048) chunks (2 tiles)
        int half = p >> 10, p1 = p & 1023;
        int n = p1 >> 3, cs = p1 & 7, c = cs ^ (n & 7), m = half * 64 + c * 8;
        *(bf16x8*)(xTt + ((size_t)b * 32 + (node0 >> 6) + half) * 8192 + p1 * 8)
            = *(const bf16x8*)(T + n * 136 + m);
    }
}

// ---------------------------------------------------------------------------
// fused layer, BM=64, 4 waves, grid 512, 2 blocks/CU (LDS 64 KB).
// A in REGISTERS (fragment-order loads, 3-deep prefetch); B in LDS quad-
// buffer staged 3-ahead by gload_lds; ONE barrier + counted vmcnt per K-step.
// AMODE 1: A-frags from fp32 adj (+cvt, +coalesced side-store to adjT).
// AMODE 2: A-frags from adjT bf16.
// Epilogue: h' = relu(LN(g @ W + bias)) -> tiled B-tile (or fp32 out).
// ---------------------------------------------------------------------------
template<int AMODE, bool FINAL>
__global__ __launch_bounds__(256, 2) void fused64(
        const float* __restrict__ Af, bf16* __restrict__ adjT,
        const bf16* __restrict__ Bt, const bf16* __restrict__ WTg,
        const float* __restrict__ bias, const float* __restrict__ gam,
        const float* __restrict__ bet, bf16* __restrict__ hOut,
        float* __restrict__ outF) {
    __shared__ __align__(16) bf16 lds[32768];   // 4 x 8192-elem B buffers

    const int tid = threadIdx.x, wave = tid >> 6, lane = tid & 63;
    const int c0 = lane & 15, q = lane >> 4;
    const int blk = blockIdx.x, xcd = blk & 7, jj = blk >> 3;
    const int b = xcd * 2 + (jj & 1);       // each XCD owns 2 batches
    const int mt = jj >> 1, m0 = mt * 64;   // [0,32) m-tiles of 64 rows

    const bf16* Btb = Bt + (size_t)b * 32 * 8192;
    bf16* Atl = adjT + ((size_t)b * 32 + mt) * (size_t)32 * 4096;
    const float* Aln = Af + (size_t)b * NN * NN
                     + (size_t)(m0 + wave * 16 + c0) * NN + q * 8;
    const int fofs = wave * 128 + lane;     // frag chunk base (+ks*64)

    f32x4 acc[8] = {};
    bf16x8 aA[4][2];     // AMODE 2 prefetch slots
    f32x4  aF[4][2][2];  // AMODE 1 prefetch slots

#define LOADA(S, KK) do {                                                     \
    if constexpr (AMODE == 1) {                                               \
        _Pragma("unroll") for (int ks = 0; ks < 2; ++ks) {                    \
            const float* s_ = Aln + (KK) * 64 + ks * 32;                      \
            aF[S][ks][0] = *(const f32x4*)s_;                                 \
            aF[S][ks][1] = *(const f32x4*)(s_ + 4);                           \
        }                                                                     \
    } else {                                                                  \
        _Pragma("unroll") for (int ks = 0; ks < 2; ++ks)                      \
            aA[S][ks] = *(const bf16x8*)(Atl + (size_t)(KK) * 4096            \
                                         + (fofs + ks * 64) * 8);             \
    } } while (0)

#define STAGEB(S, KK) do {                                                    \
    _Pragma("unroll") for (int j = 0; j < 4; ++j) {                           \
        int cb = j * 256 + wave * 64;                                         \
        gload_lds16(Btb + (size_t)(KK) * 8192 + (size_t)(cb + lane) * 8,      \
                    lds + (S) * 8192 + cb * 8);                               \
    } } while (0)

#define COMP(S, KK) do {                                                      \
    bf16x8 af_[2];                                                            \
    if constexpr (AMODE == 1) {                                               \
        _Pragma("unroll") for (int ks = 0; ks < 2; ++ks) {                    \
            f32x4 lo = aF[S][ks][0], hi = aF[S][ks][1];                       \
            bf16x8 o = {(bf16)lo.x, (bf16)lo.y, (bf16)lo.z, (bf16)lo.w,       \
                        (bf16)hi.x, (bf16)hi.y, (bf16)hi.z, (bf16)hi.w};      \
            af_[ks] = o;                                                      \
            *(bf16x8*)(Atl + (size_t)(KK) * 4096 + (fofs + ks * 64) * 8) = o; \
        }                                                                     \
    } else { af_[0] = aA[S][0]; af_[1] = aA[S][1]; }                          \
    const bf16* Bs_ = lds + (S) * 8192;                                       \
    _Pragma("unroll") for (int ks = 0; ks < 2; ++ks)                          \
        _Pragma("unroll") for (int nt = 0; nt < 8; ++nt) {                    \
            int row = nt * 16 + c0, cb = (ks * 4 + q) ^ (row & 7);            \
            bf16x8 bw = *(const bf16x8*)(Bs_ + row * 64 + cb * 8);            \
            acc[nt] = __builtin_amdgcn_mfma_f32_16x16x32_bf16(                \
                af_[ks], bw, acc[nt], 0, 0, 0);                               \
        } } while (0)

    // prologue: tiles 0,1,2 in flight (A->regs, B->LDS bufs 0..2)
    LOADA(0, 0); STAGEB(0, 0);
    LOADA(1, 1); STAGEB(1, 1);
    LOADA(2, 2); STAGEB(2, 2);

    // main: kk = 0..27.  steady-state wait leaves 2 tiles in flight:
    //   AMODE2: 2 x (2A+4B) = 12;  AMODE1: 2 x (2st + 4A+4B) = 20.
#define ITERU(U, KB)                                                          \
    { if constexpr (AMODE == 1) WAITV(20); else WAITV(12);                    \
      __builtin_amdgcn_s_barrier();                                           \
      COMP(U, (KB) + (U));                                                    \
      LOADA(((U) + 3) & 3, (KB) + (U) + 3);                                   \
      STAGEB(((U) + 3) & 3, (KB) + (U) + 3); }

#pragma unroll 1
    for (int t = 0; t < 7; ++t) {
        const int kb = t * 4;
        ITERU(0, kb) ITERU(1, kb) ITERU(2, kb) ITERU(3, kb)
    }
    // tail kk = 28..31
    if constexpr (AMODE == 1) WAITV(20); else WAITV(12);
    __builtin_amdgcn_s_barrier();
    COMP(0, 28);
    LOADA(3, 31); STAGEB(3, 31);

    if constexpr (AMODE == 1) WAITV(20); else WAITV(12);
    __builtin_amdgcn_s_barrier();
    COMP(1, 29);

    if constexpr (AMODE == 1) WAITV(12); else WAITV(6);
    __builtin_amdgcn_s_barrier();
    COMP(2, 30);

    if constexpr (AMODE == 1) WAITV(4); else WAITV(0);
    __builtin_amdgcn_s_barrier();
    COMP(3, 31);

#undef ITERU
#undef COMP
#undef STAGEB
#undef LOADA

    __syncthreads();    // all compute done; B buffers dead

    // stage WT (2048 chunks) into bufs 2,3 region [16384,32768)
#pragma unroll
    for (int j = 0; j < 8; ++j) {
        int cb = j * 256 + wave * 64;
        gload_lds16(WTg + (size_t)(cb + lane) * 8, lds + 16384 + cb * 8);
    }
    // write g-tile bf16 to G = lds[0..8704) as [64][136]
    bf16* G = lds;
#pragma unroll
    for (int nt = 0; nt < 8; ++nt)
#pragma unroll
        for (int r = 0; r < 4; ++r) {
            int row = wave * 16 + q * 4 + r;
            G[row * 136 + nt * 16 + c0] = (bf16)acc[nt][r];
        }
    WAITV(0);
    __syncthreads();

    // W-GEMM: h(64x128) = G @ W ; wave owns rows [wave*16, wave*16+16)
    f32x4 a2[8] = {};
    {
        const int gr = wave * 16 + c0;
#pragma unroll
        for (int ks = 0; ks < 4; ++ks) {
            bf16x8 af = *(const bf16x8*)(G + gr * 136 + ks * 32 + q * 8);
#pragma unroll
            for (int nt = 0; nt < 8; ++nt) {
                int n = nt * 16 + c0;
                int ch = n * 16 + (ks >> 1) * 8 + ((((ks & 1) << 2) | q) ^ (n & 7));
                a2[nt] = __builtin_amdgcn_mfma_f32_16x16x32_bf16(
                    af, *(const bf16x8*)(lds + 16384 + ch * 8), a2[nt], 0, 0, 0);
            }
        }
    }

    // bias + LN(over n=128) + ReLU
    float bv[8], gv[8], ev[8];
#pragma unroll
    for (int nt = 0; nt < 8; ++nt) {
        int n = nt * 16 + c0;
        bv[nt] = bias[n]; gv[nt] = gam[n]; ev[nt] = bet[n];
    }
    bf16* Cs = lds;   // [128 n][72] node-minor; aliases G (post-barrier)
    if constexpr (!FINAL) __syncthreads();   // all W-GEMM reads of G done
#pragma unroll
    for (int r = 0; r < 4; ++r) {
        float v[8], s1 = 0.f, s2 = 0.f;
#pragma unroll
        for (int nt = 0; nt < 8; ++nt) {
            float xv = a2[nt][r] + bv[nt];
            v[nt] = xv; s1 += xv; s2 += xv * xv;
        }
#pragma unroll
        for (int off = 1; off < 16; off <<= 1) {
            s1 += __shfl_xor(s1, off);
            s2 += __shfl_xor(s2, off);
        }
        float mu = s1 * (1.f / 128.f);
        float var = s2 * (1.f / 128.f) - mu * mu;
        float rs = rsqrtf(var + 1e-5f);
        int row = wave * 16 + q * 4 + r;      // local node row in [0,64)
        if constexpr (FINAL) {
            size_t ro = ((size_t)b * NN + m0 + row) * HID;
#pragma unroll
            for (int nt = 0; nt < 8; ++nt) {
                float o = fmaxf((v[nt] - mu) * rs * gv[nt] + ev[nt], 0.f);
                outF[ro + nt * 16 + c0] = o;
            }
        } else {
#pragma unroll
            for (int nt = 0; nt < 8; ++nt) {
                float o = fmaxf((v[nt] - mu) * rs * gv[nt] + ev[nt], 0.f);
                Cs[(nt * 16 + c0) * 72 + row] = (bf16)o;
            }
        }
    }
    if constexpr (!FINAL) {
        __syncthreads();
        // write this block's B-tile (kk = mt), fully linear
#pragma unroll
        for (int i = 0; i < 4; ++i) {
            int p1 = i * 256 + tid;           // [0,1024)
            int n = p1 >> 3, cs = p1 & 7, c = cs ^ (n & 7), m = c * 8;
            *(bf16x8*)(hOut + ((size_t)b * 32 + mt) * 8192 + p1 * 8)
                = *(const bf16x8*)(Cs + n * 72 + m);
        }
    }
}

// ---------------------------------------------------------------------------
extern "C" void kernel_launch(void* const* d_in, const int* in_sizes, int n_in,
                              void* d_out, int out_size, void* d_ws, size_t ws_size,
                              hipStream_t stream) {
    const float* x   = (const float*)d_in[0];
    const float* adj = (const float*)d_in[1];
    const float* W[3]  = {(const float*)d_in[2],  (const float*)d_in[6],  (const float*)d_in[10]};
    const float* bb[3] = {(const float*)d_in[3],  (const float*)d_in[7],  (const float*)d_in[11]};
    const float* gg[3] = {(const float*)d_in[4],  (const float*)d_in[8],  (const float*)d_in[12]};
    const float* be[3] = {(const float*)d_in[5],  (const float*)d_in[9],  (const float*)d_in[13]};

    char* ws = (char*)d_ws;
    size_t off = 0;
    auto alloc = [&](size_t bytes) {
        char* p = ws + off; off = (off + bytes + 255) & ~(size_t)255; return p;
    };
    bf16* WTg  = (bf16*)alloc((size_t)3 * 16384 * 2);
    bf16* xTt  = (bf16*)alloc((size_t)NB * 32 * 8192 * 2);            // 8 MiB
    bf16* hT0  = (bf16*)alloc((size_t)NB * 32 * 8192 * 2);            // 8 MiB
    bf16* hT1  = (bf16*)alloc((size_t)NB * 32 * 8192 * 2);            // 8 MiB
    bf16* adjT = (bf16*)alloc((size_t)NB * 32 * 32 * 4096 * 2);       // 128 MiB

    float* outF = (float*)d_out;

    prep_wt<<<3, 256, 0, stream>>>(W[0], W[1], W[2], WTg);
    prep_xt<<<256, 256, 0, stream>>>(x, xTt);

    fused64<1, false><<<512, 256, 0, stream>>>(adj, adjT, xTt, WTg,
                                               bb[0], gg[0], be[0], hT0, nullptr);
    fused64<2, false><<<512, 256, 0, stream>>>(adj, adjT, hT0, WTg + 16384,
                                               bb[1], gg[1], be[1], hT1, nullptr);
    fused64<2, true ><<<512, 256, 0, stream>>>(adj, adjT, hT1, WTg + 2 * 16384,
                                               bb[2], gg[2], be[2], nullptr, outF);
}